// Round 6
// baseline (157.769 us; speedup 1.0000x reference)
//
#include <hip/hip_runtime.h>
#include <hip/hip_bf16.h>

// LSTM_71382356459716 R5: two fixes driven by R4 counters.
// (1) Activations: exp+rcp sigmoid/tanh cost 2 trans ops each; measured VALU
//     busy (39us) only fits if wave64 trans = 16 cyc (1/8 rate) -> ~30us
//     trans-pipe floor. Replaced with Pade(7,6) rational tanh (+clamp) and
//     sigma(v)=0.5+0.5*tanh(v/2) with prescaled coefficients: 10-11 full-rate
//     ops + ONE rcp per activation. |err| <= 1.4e-4 << bf16 h-rounding.
// (2) x loads: R4's direct-from-global was 4x redundant (all 4 waves load the
//     same (l15,q) slice). x now staged once per block into LDS as bf16 in
//     the same row as h: k 0..27 = x, k28 = 1.0 (bias column), k32..95 = h.
//     B-frags = 3 conflict-free ds_read_b128; staging = 112 threads * float4.
// Structure kept from R4: 1024 blocks x 4 waves, wave owns 16 units (4 M-tiles
// stationary in regs, bias folded into W col 28), block owns 16 rows,
// double-buffered LDS rows of 104 shorts (208B = odd multiple of 16B).

namespace {
constexpr int B_TOT   = 16384;
constexpr int T_STEPS = 28;
constexpr int IN_DIM  = 28;
constexpr int HID     = 64;
constexpr int OUT_DIM = 10;
constexpr int ROWS    = 16;    // batch rows per block -> 1024 blocks, 4/CU
constexpr int THREADS = 256;   // 4 waves
constexpr int KP      = 104;   // row stride in shorts (208 B, odd*16B)
constexpr int XROW    = T_STEPS * IN_DIM;  // 784 floats per batch row
}

typedef __attribute__((ext_vector_type(8))) short short8v;   // 8 bf16
typedef __attribute__((ext_vector_type(4))) short short4v;
typedef __attribute__((ext_vector_type(4))) float float4v;

__device__ __forceinline__ short f2bf_cold(float f) {   // init path only
  union { float f; unsigned u; } v; v.f = f;
  unsigned r = v.u + 0x7FFFu + ((v.u >> 16) & 1u);
  return (short)(r >> 16);
}
__device__ __forceinline__ float bf2f(short s) {
  union { unsigned u; float f; } v; v.u = ((unsigned)(unsigned short)s) << 16;
  return v.f;
}
__device__ __forceinline__ unsigned pk2(float a, float b) {  // 2xf32->bf16x2
  __hip_bfloat162 h = __float22bfloat162_rn(float2{a, b});
  union { __hip_bfloat162 h; unsigned u; } cv; cv.h = h; return cv.u;
}

// tanh via Pade(7,6) (Lambert CF truncation), clamped to [-1,1].
// Max abs err ~1.4e-4 (worst near |x|~4.7); exact for the x->inf tail via clamp.
__device__ __forceinline__ float tanh_pade(float x) {
  float w = x * x;
  float p = (w + 378.0f) * w + 17325.0f;
  p = p * w + 135135.0f;
  float num = x * p;
  float q = 28.0f * w + 3150.0f;
  q = q * w + 62370.0f;
  q = q * w + 135135.0f;
  float t = num * __builtin_amdgcn_rcpf(q);
  return fminf(fmaxf(t, -1.0f), 1.0f);
}
// sigmoid(v) = 0.5 + 0.5*tanh(v/2); the /2 is prescaled into the coefficients.
__device__ __forceinline__ float sig_pade(float v) {
  float w = v * v;
  float p = w * (1.0f / 128.0f) + 11.8125f;
  p = p * w + 2165.625f;
  p = p * w + 67567.5f;
  float num = v * p;
  float q = 0.4375f * w + 196.875f;
  q = q * w + 15592.5f;
  q = q * w + 135135.0f;
  float t = num * __builtin_amdgcn_rcpf(q);
  t = fminf(fmaxf(t, -1.0f), 1.0f);
  return fmaf(t, 0.5f, 0.5f);
}

__global__ __attribute__((amdgpu_flat_work_group_size(THREADS, THREADS),
                          amdgpu_waves_per_eu(4, 4)))
void lstm_mfma5(const float* __restrict__ x, const float* __restrict__ W_ih,
                const float* __restrict__ W_hh, const float* __restrict__ b_ih,
                const float* __restrict__ b_hh, const float* __restrict__ W_fc,
                const float* __restrict__ b_fc, float* __restrict__ out) {
  __shared__ short hs[2][ROWS][KP];   // [buf][row][k]: 0..27 x, 28 = 1.0, 32..95 h

  const int tid  = threadIdx.x;
  const int lane = tid & 63;
  const int w    = tid >> 6;      // wave 0..3 -> units 16w..16w+15
  const int l15  = lane & 15;
  const int q    = lane >> 4;     // 0..3
  const int b0   = blockIdx.x * ROWS;

  // ---- stationary A (weights + bias col 28), gate rows permuted unit-major
  // A-frag: lane holds A[m = 16*mt + l15][k = kc*32 + q*8 + j].
  short8v a[4][3];
#pragma unroll
  for (int i = 0; i < 4; ++i) {
    const int mt   = 4 * w + i;
    const int m    = 16 * mt + l15;
    const int unit = m >> 2, type = m & 3;
    const int g    = type * 64 + unit;
#pragma unroll
    for (int kc = 0; kc < 3; ++kc) {
      short8v frag;
#pragma unroll
      for (int j = 0; j < 8; ++j) {
        const int k = kc * 32 + q * 8 + j;
        float v = 0.0f;
        if (k < IN_DIM)        v = W_ih[g * IN_DIM + k];
        else if (k == IN_DIM)  v = b_ih[g] + b_hh[g];     // bias column
        else if (k >= 32)      v = W_hh[g * HID + (k - 32)];
        frag[j] = f2bf_cold(v);
      }
      a[i][kc] = frag;
    }
  }

  // zero both buffers, then set the constant bias column (never overwritten)
  for (int idx = tid; idx < 2 * ROWS * KP; idx += THREADS) (&hs[0][0][0])[idx] = 0;
  __syncthreads();
  if (tid < 2 * ROWS) hs[tid >> 4][tid & 15][IN_DIM] = (short)0x3F80;  // bf16 1.0

  // ---- x staging: 112 threads, one float4 (4 x-values) each per step -------
  const bool stager = (tid < ROWS * 7);
  const int  sr = tid / 7;            // row 0..15
  const int  sc = tid - 7 * sr;       // col-group 0..6 -> k = 4*sc..4*sc+3
  const float* xptr = x + (size_t)(b0 + sr) * XROW + sc * 4;

  // stage x_0
  if (stager) {
    float4 xv = *(const float4*)xptr;
    short4v s;
    unsigned plo = pk2(xv.x, xv.y), phi = pk2(xv.z, xv.w);
    s[0] = (short)(plo & 0xFFFF); s[1] = (short)(plo >> 16);
    s[2] = (short)(phi & 0xFFFF); s[3] = (short)(phi >> 16);
    *(short4v*)&hs[0][sr][sc * 4] = s;
  }
  __syncthreads();

  float c_state[4] = {0.f, 0.f, 0.f, 0.f};

  for (int t = 0; t < T_STEPS; ++t) {
    const int cur = t & 1, nxt = cur ^ 1;

    // global load of x_{t+1} (latency hides under MFMA + activations)
    float4 xv;
    const bool doStage = stager && (t + 1 < T_STEPS);
    if (doStage) xv = *(const float4*)(xptr + (t + 1) * IN_DIM);

    // B-frags: lane holds B[k = kc*32 + q*8 + j][n = l15]
    short8v bf0 = *(const short8v*)&hs[cur][l15][q * 8];
    short8v bf1 = *(const short8v*)&hs[cur][l15][32 + q * 8];
    short8v bf2 = *(const short8v*)&hs[cur][l15][64 + q * 8];

    const float4v zero4 = {0.f, 0.f, 0.f, 0.f};
    float4v acc[4];
#pragma unroll
    for (int i = 0; i < 4; ++i)
      acc[i] = __builtin_amdgcn_mfma_f32_16x16x32_bf16(a[i][0], bf0, zero4, 0, 0, 0);
#pragma unroll
    for (int i = 0; i < 4; ++i)
      acc[i] = __builtin_amdgcn_mfma_f32_16x16x32_bf16(a[i][1], bf1, acc[i], 0, 0, 0);
#pragma unroll
    for (int i = 0; i < 4; ++i)
      acc[i] = __builtin_amdgcn_mfma_f32_16x16x32_bf16(a[i][2], bf2, acc[i], 0, 0, 0);

    // write x_{t+1} into the other buffer (its x-region was last read at t-1;
    // the barrier at end of t-1 makes this safe)
    if (doStage) {
      short4v s;
      unsigned plo = pk2(xv.x, xv.y), phi = pk2(xv.z, xv.w);
      s[0] = (short)(plo & 0xFFFF); s[1] = (short)(plo >> 16);
      s[2] = (short)(phi & 0xFFFF); s[3] = (short)(phi >> 16);
      *(short4v*)&hs[nxt][sr][sc * 4] = s;
    }

    // activations + state update; lane-local (regs 0..3 = i,f,g,o of one unit)
    float hv[4];
#pragma unroll
    for (int i = 0; i < 4; ++i) {
      float4v g4 = acc[i];
      float iv = sig_pade(g4[0]);
      float fv = sig_pade(g4[1]);
      float gv = tanh_pade(g4[2]);
      float ov = sig_pade(g4[3]);
      float cn = fv * c_state[i] + iv * gv;
      c_state[i] = cn;
      hv[i] = ov * tanh_pade(cn);
    }
    // packed bf16 convert, 4 b16 stores (unit 16w+4i+q, row l15)
    unsigned p01 = pk2(hv[0], hv[1]);
    unsigned p23 = pk2(hv[2], hv[3]);
    hs[nxt][l15][32 + 16 * w + 0 + q]  = (short)(p01 & 0xFFFF);
    hs[nxt][l15][32 + 16 * w + 4 + q]  = (short)(p01 >> 16);
    hs[nxt][l15][32 + 16 * w + 8 + q]  = (short)(p23 & 0xFFFF);
    hs[nxt][l15][32 + 16 * w + 12 + q] = (short)(p23 >> 16);

    __syncthreads();
  }

  // ---- FC epilogue: final h in hs[0] (t=27 wrote nxt = 0), cols 32..95 -----
  if (tid < ROWS * OUT_DIM) {           // 160 outputs
    const int r = tid / OUT_DIM;
    const int o = tid - r * OUT_DIM;
    float s = b_fc[o];
#pragma unroll
    for (int j = 0; j < HID; ++j)
      s += bf2f(hs[0][r][32 + j]) * W_fc[o * HID + j];
    out[(b0 + r) * OUT_DIM + o] = s;
  }
}

extern "C" void kernel_launch(void* const* d_in, const int* in_sizes, int n_in,
                              void* d_out, int out_size, void* d_ws, size_t ws_size,
                              hipStream_t stream) {
  const float* x    = (const float*)d_in[0];
  const float* W_ih = (const float*)d_in[1];
  const float* W_hh = (const float*)d_in[2];
  const float* b_ih = (const float*)d_in[3];
  const float* b_hh = (const float*)d_in[4];
  const float* W_fc = (const float*)d_in[5];
  const float* b_fc = (const float*)d_in[6];
  float* out = (float*)d_out;

  dim3 grid(B_TOT / ROWS);   // 1024 blocks -> 4 blocks/CU co-resident
  dim3 block(THREADS);
  lstm_mfma5<<<grid, block, 0, stream>>>(x, W_ih, W_hh, b_ih, b_hh, W_fc, b_fc, out);
}

// Round 7
// 133.139 us; speedup vs baseline: 1.1850x; 1.1850x over previous
//
#include <hip/hip_runtime.h>
#include <hip/hip_bf16.h>

// LSTM_71382356459716 R6: R4 structure + deep x-prefetch + x via LDS stagers.
// R5 post-mortem: Pade activations regressed (literal-materialization makes
// them ~2x the VALU issue of exp-form at trans=16cyc) -> back to exp/rcp.
// R4/R5's residual stall traced to the x prefetch being consumed ~150 cyc
// after issue (only 12 MFMAs of cover vs global latency 200-900 cyc), which
// serializes through the per-step barrier. Fix: two-step-deep pipeline --
// at step t the 112 stagers STORE x_{t+1} (loaded back at t-1: a full step
// of vmcnt slack) and ISSUE the load of x_{t+2}.
// Kept: 1024 blocks x 4 waves (4 indep barrier groups/CU), wave owns 16
// units (4 M-tiles stationary in regs, bias folded into W col 28 against a
// constant-1 x column), block owns 16 rows, double-buffered LDS rows of
// 104 shorts (208 B stride), 3 conflict-free ds_read_b128 B-frags, 1 barrier.

namespace {
constexpr int B_TOT   = 16384;
constexpr int T_STEPS = 28;
constexpr int IN_DIM  = 28;
constexpr int HID     = 64;
constexpr int OUT_DIM = 10;
constexpr int ROWS    = 16;    // batch rows per block -> 1024 blocks, 4/CU
constexpr int THREADS = 256;   // 4 waves
constexpr int KP      = 104;   // row stride in shorts (208 B, odd*16B)
constexpr int XROW    = T_STEPS * IN_DIM;  // 784 floats per batch row
}

typedef __attribute__((ext_vector_type(8))) short short8v;   // 8 bf16
typedef __attribute__((ext_vector_type(4))) short short4v;
typedef __attribute__((ext_vector_type(4))) float float4v;

__device__ __forceinline__ short f2bf_cold(float f) {   // init path only
  union { float f; unsigned u; } v; v.f = f;
  unsigned r = v.u + 0x7FFFu + ((v.u >> 16) & 1u);
  return (short)(r >> 16);
}
__device__ __forceinline__ float bf2f(short s) {
  union { unsigned u; float f; } v; v.u = ((unsigned)(unsigned short)s) << 16;
  return v.f;
}
__device__ __forceinline__ unsigned pk2(float a, float b) {  // 2xf32->bf16x2
  __hip_bfloat162 h = __float22bfloat162_rn(float2{a, b});
  union { __hip_bfloat162 h; unsigned u; } cv; cv.h = h; return cv.u;
}
__device__ __forceinline__ float sigf(float v) {
  return __builtin_amdgcn_rcpf(1.0f + __expf(-v));
}
__device__ __forceinline__ float tanh_f(float v) {
  return 2.0f * __builtin_amdgcn_rcpf(1.0f + __expf(-2.0f * v)) - 1.0f;
}

__global__ __attribute__((amdgpu_flat_work_group_size(THREADS, THREADS),
                          amdgpu_waves_per_eu(4, 4)))
void lstm_mfma6(const float* __restrict__ x, const float* __restrict__ W_ih,
                const float* __restrict__ W_hh, const float* __restrict__ b_ih,
                const float* __restrict__ b_hh, const float* __restrict__ W_fc,
                const float* __restrict__ b_fc, float* __restrict__ out) {
  __shared__ short hs[2][ROWS][KP];   // [buf][row][k]: 0..27 x, 28 = 1.0, 32..95 h

  const int tid  = threadIdx.x;
  const int lane = tid & 63;
  const int w    = tid >> 6;      // wave 0..3 -> units 16w..16w+15
  const int l15  = lane & 15;
  const int q    = lane >> 4;     // 0..3
  const int b0   = blockIdx.x * ROWS;

  // ---- stationary A (weights + bias col 28), gate rows permuted unit-major
  // A-frag: lane holds A[m = 16*mt + l15][k = kc*32 + q*8 + j].
  short8v a[4][3];
#pragma unroll
  for (int i = 0; i < 4; ++i) {
    const int mt   = 4 * w + i;
    const int m    = 16 * mt + l15;
    const int unit = m >> 2, type = m & 3;
    const int g    = type * 64 + unit;
#pragma unroll
    for (int kc = 0; kc < 3; ++kc) {
      short8v frag;
#pragma unroll
      for (int j = 0; j < 8; ++j) {
        const int k = kc * 32 + q * 8 + j;
        float v = 0.0f;
        if (k < IN_DIM)        v = W_ih[g * IN_DIM + k];
        else if (k == IN_DIM)  v = b_ih[g] + b_hh[g];     // bias column
        else if (k >= 32)      v = W_hh[g * HID + (k - 32)];
        frag[j] = f2bf_cold(v);
      }
      a[i][kc] = frag;
    }
  }

  // zero both buffers, then set the constant bias column (never overwritten)
  for (int idx = tid; idx < 2 * ROWS * KP; idx += THREADS) (&hs[0][0][0])[idx] = 0;
  __syncthreads();
  if (tid < 2 * ROWS) hs[tid >> 4][tid & 15][IN_DIM] = (short)0x3F80;  // bf16 1.0

  // ---- x staging: 112 threads, one float4 (4 x-values) each per step -------
  const bool stager = (tid < ROWS * 7);
  const int  sr = tid / 7;            // row 0..15
  const int  sc = tid - 7 * sr;       // col-group 0..6 -> k = 4*sc..4*sc+3
  const float* xptr = x + (size_t)(b0 + sr) * XROW + sc * 4;

  // stage x_0 directly; preload x_1 into the in-flight register
  float4 xfly = {0.f, 0.f, 0.f, 0.f};
  if (stager) {
    float4 x0 = *(const float4*)xptr;
    short4v s;
    unsigned plo = pk2(x0.x, x0.y), phi = pk2(x0.z, x0.w);
    s[0] = (short)(plo & 0xFFFF); s[1] = (short)(plo >> 16);
    s[2] = (short)(phi & 0xFFFF); s[3] = (short)(phi >> 16);
    *(short4v*)&hs[0][sr][sc * 4] = s;
    xfly = *(const float4*)(xptr + 1 * IN_DIM);   // x_1, consumed at t=0
  }
  __syncthreads();

  float c_state[4] = {0.f, 0.f, 0.f, 0.f};

  for (int t = 0; t < T_STEPS; ++t) {
    const int cur = t & 1, nxt = cur ^ 1;

    // B-frags: lane holds B[k = kc*32 + q*8 + j][n = l15]
    short8v bf0 = *(const short8v*)&hs[cur][l15][q * 8];
    short8v bf1 = *(const short8v*)&hs[cur][l15][32 + q * 8];
    short8v bf2 = *(const short8v*)&hs[cur][l15][64 + q * 8];

    // store x_{t+1} (loaded a full step ago -> vmcnt long since retired),
    // then issue the load of x_{t+2} (consumed next step).
    if (stager) {
      if (t + 1 < T_STEPS) {
        short4v s;
        unsigned plo = pk2(xfly.x, xfly.y), phi = pk2(xfly.z, xfly.w);
        s[0] = (short)(plo & 0xFFFF); s[1] = (short)(plo >> 16);
        s[2] = (short)(phi & 0xFFFF); s[3] = (short)(phi >> 16);
        *(short4v*)&hs[nxt][sr][sc * 4] = s;
      }
      if (t + 2 < T_STEPS)
        xfly = *(const float4*)(xptr + (t + 2) * IN_DIM);
    }

    const float4v zero4 = {0.f, 0.f, 0.f, 0.f};
    float4v acc[4];
#pragma unroll
    for (int i = 0; i < 4; ++i)
      acc[i] = __builtin_amdgcn_mfma_f32_16x16x32_bf16(a[i][0], bf0, zero4, 0, 0, 0);
#pragma unroll
    for (int i = 0; i < 4; ++i)
      acc[i] = __builtin_amdgcn_mfma_f32_16x16x32_bf16(a[i][1], bf1, acc[i], 0, 0, 0);
#pragma unroll
    for (int i = 0; i < 4; ++i)
      acc[i] = __builtin_amdgcn_mfma_f32_16x16x32_bf16(a[i][2], bf2, acc[i], 0, 0, 0);

    // activations + state update; lane-local (regs 0..3 = i,f,g,o of one unit)
    float hv[4];
#pragma unroll
    for (int i = 0; i < 4; ++i) {
      float4v g4 = acc[i];
      float iv = sigf(g4[0]);
      float fv = sigf(g4[1]);
      float gv = tanh_f(g4[2]);
      float ov = sigf(g4[3]);
      float cn = fv * c_state[i] + iv * gv;
      c_state[i] = cn;
      hv[i] = ov * tanh_f(cn);
    }
    // packed bf16 convert, 4 b16 stores (unit 16w+4i+q, row l15)
    unsigned p01 = pk2(hv[0], hv[1]);
    unsigned p23 = pk2(hv[2], hv[3]);
    hs[nxt][l15][32 + 16 * w + 0 + q]  = (short)(p01 & 0xFFFF);
    hs[nxt][l15][32 + 16 * w + 4 + q]  = (short)(p01 >> 16);
    hs[nxt][l15][32 + 16 * w + 8 + q]  = (short)(p23 & 0xFFFF);
    hs[nxt][l15][32 + 16 * w + 12 + q] = (short)(p23 >> 16);

    __syncthreads();
  }

  // ---- FC epilogue: final h in hs[0] (t=27 wrote nxt = 0), cols 32..95 -----
  if (tid < ROWS * OUT_DIM) {           // 160 outputs
    const int r = tid / OUT_DIM;
    const int o = tid - r * OUT_DIM;
    float s = b_fc[o];
#pragma unroll
    for (int j = 0; j < HID; ++j)
      s += bf2f(hs[0][r][32 + j]) * W_fc[o * HID + j];
    out[(b0 + r) * OUT_DIM + o] = s;
  }
}

extern "C" void kernel_launch(void* const* d_in, const int* in_sizes, int n_in,
                              void* d_out, int out_size, void* d_ws, size_t ws_size,
                              hipStream_t stream) {
  const float* x    = (const float*)d_in[0];
  const float* W_ih = (const float*)d_in[1];
  const float* W_hh = (const float*)d_in[2];
  const float* b_ih = (const float*)d_in[3];
  const float* b_hh = (const float*)d_in[4];
  const float* W_fc = (const float*)d_in[5];
  const float* b_fc = (const float*)d_in[6];
  float* out = (float*)d_out;

  dim3 grid(B_TOT / ROWS);   // 1024 blocks -> 4 blocks/CU co-resident
  dim3 block(THREADS);
  lstm_mfma6<<<grid, block, 0, stream>>>(x, W_ih, W_hh, b_ih, b_hh, W_fc, b_fc, out);
}